// Round 2
// baseline (322.051 us; speedup 1.0000x reference)
//
#include <hip/hip_runtime.h>
#include <hip/hip_bf16.h>

typedef unsigned int u32;
typedef unsigned short u16;

#define B_      128
#define N_      4096
#define D_      64
#define K_      8
#define H_      128
#define ITERS_  3
#define NCHUNK  16
#define CHUNK   256          // positions per bigpass block
#define SCALE_  0.125f
#define EPS_A   1e-8f
#define EPS_LN  1e-5f

__device__ __forceinline__ float bf_lo(u32 u){ union{u32 v; float f;} x; x.v = u<<16; return x.f; }
__device__ __forceinline__ float bf_hi(u32 u){ union{u32 v; float f;} x; x.v = u & 0xffff0000u; return x.f; }
__device__ __forceinline__ u16 f2bf(float f){
  union{float f; u32 v;} x; x.f = f;
  u32 v = x.v;
  return (u16)((v + 0x7fffu + ((v>>16)&1u))>>16);   // RNE
}
__device__ __forceinline__ float wsum64(float v){
  #pragma unroll
  for (int off=32; off; off>>=1) v += __shfl_xor(v, off, 64);
  return v;
}

// ---------------- transpose GRU weights once: W[g][d] -> WT[d][g] ----------------
__global__ void prep_t(const float* __restrict__ Wih, const float* __restrict__ Whh,
                       float* __restrict__ WihT, float* __restrict__ WhhT){
  int idx = blockIdx.x*256 + threadIdx.x;   // 192*64 = 12288
  if (idx < 192*64){
    int g = idx>>6, d = idx&63;
    WihT[d*192+g] = Wih[idx];
    WhhT[d*192+g] = Whh[idx];
  }
}

// ---------------- slots0 = mu + sigma*noise ; q0 = LN(slots0) @ Wq ----------------
__global__ __launch_bounds__(512) void slots_init(
    const float* __restrict__ noise, const float* __restrict__ mu, const float* __restrict__ sigma,
    const float* __restrict__ Wq, const float* __restrict__ lnsg, const float* __restrict__ lnsb,
    float* __restrict__ slots, float* __restrict__ qbuf){
  int b = blockIdx.x, t = threadIdx.x;
  int i = t>>6, d = t&63;
  __shared__ float svL[K_][68];
  float s0 = mu[d] + sigma[d]*noise[b*512 + t];
  slots[b*512 + t] = s0;
  float m  = wsum64(s0) * (1.f/64.f);
  float df = s0 - m;
  float vv = wsum64(df*df) * (1.f/64.f);
  float sv = df * rsqrtf(vv + EPS_LN) * lnsg[d] + lnsb[d];
  svL[i][d] = sv;
  __syncthreads();
  float acc = 0.f;
  #pragma unroll 8
  for (int dd=0; dd<64; ++dd) acc += svL[i][dd] * Wq[dd*64 + d];
  qbuf[b*512 + t] = acc;
}

// ---------------- x = LN(inputs); k = x@Wk, v = x@Wv  (bf16 out) ----------------
__global__ __launch_bounds__(256) void kv_kernel(
    const float* __restrict__ inp, const float* __restrict__ Wk, const float* __restrict__ Wv,
    const float* __restrict__ lng, const float* __restrict__ lnb,
    u16* __restrict__ kout, u16* __restrict__ vout){
  __shared__ float xT[64*68];      // x transposed [d][row], stride 68
  __shared__ float Wc[64*132];     // [d][Wk cols 0..63 | Wv cols 64..127], stride 132
  __shared__ float psum[64][4];
  __shared__ float psq[64][4];
  int t = threadIdx.x;

  // stage weights (8192 floats, coalesced)
  #pragma unroll
  for (int m=0; m<32; ++m){
    int idx = t + m*256;
    int dd = idx>>7, j = idx&127;
    Wc[dd*132 + j] = (j<64) ? Wk[dd*64+j] : Wv[dd*64 + (j-64)];
  }
  // load 64-row x tile + LayerNorm
  long r0 = (long)blockIdx.x*64;
  int r = t>>2, part = t&3;
  const float4* xrow = (const float4*)(inp + (r0 + r)*64 + part*16);
  float xv[16]; float s=0.f, sq=0.f;
  #pragma unroll
  for (int c=0;c<4;++c){
    float4 f = xrow[c];
    xv[c*4+0]=f.x; xv[c*4+1]=f.y; xv[c*4+2]=f.z; xv[c*4+3]=f.w;
    s  += f.x+f.y+f.z+f.w;
    sq += f.x*f.x+f.y*f.y+f.z*f.z+f.w*f.w;
  }
  psum[r][part]=s; psq[r][part]=sq;
  __syncthreads();
  float fs = psum[r][0]+psum[r][1]+psum[r][2]+psum[r][3];
  float fq = psq[r][0]+psq[r][1]+psq[r][2]+psq[r][3];
  float mean = fs*(1.f/64.f);
  float var  = fq*(1.f/64.f) - mean*mean;
  float inv  = rsqrtf(var + EPS_LN);
  #pragma unroll
  for (int e=0;e<16;++e){
    int dd = part*16+e;
    xT[dd*68 + r] = (xv[e]-mean)*inv*lng[dd] + lnb[dd];
  }
  __syncthreads();
  // register-tile GEMM: 4 rows x 8 cols per thread
  int tr = t>>4, tc = t&15;
  float acc[4][8];
  #pragma unroll
  for(int a=0;a<4;++a){
    #pragma unroll
    for(int bb=0;bb<8;++bb) acc[a][bb]=0.f;
  }
  #pragma unroll 4
  for (int dd=0; dd<64; ++dd){
    float4 x4 = *(const float4*)&xT[dd*68 + tr*4];
    #pragma unroll
    for (int m=0;m<4;++m){
      float2 w = *(const float2*)&Wc[dd*132 + 2*tc + 32*m];
      acc[0][2*m] += x4.x*w.x; acc[0][2*m+1] += x4.x*w.y;
      acc[1][2*m] += x4.y*w.x; acc[1][2*m+1] += x4.y*w.y;
      acc[2][2*m] += x4.z*w.x; acc[2][2*m+1] += x4.z*w.y;
      acc[3][2*m] += x4.w*w.x; acc[3][2*m+1] += x4.w*w.y;
    }
  }
  u32* kp = (u32*)kout; u32* vp = (u32*)vout;
  #pragma unroll
  for (int rr=0; rr<4; ++rr){
    long grow = r0 + tr*4 + rr;
    #pragma unroll
    for (int m=0;m<4;++m){
      u32 lo = f2bf(acc[rr][2*m]);
      u32 hi = f2bf(acc[rr][2*m+1]);
      u32 u  = lo | (hi<<16);
      if (m<2) kp[grow*32 + tc + 16*m]     = u;
      else     vp[grow*32 + tc + 16*(m-2)] = u;
    }
  }
}

// ---------------- fused dots/softmax-over-K/partial S,U per (b,chunk) ----------------
__global__ __launch_bounds__(256) void bigpass(
    const u16* __restrict__ kbf, const u16* __restrict__ vbf,
    const float* __restrict__ qbuf,
    float* __restrict__ PU, float* __restrict__ PS){
  int b = blockIdx.y, chunk = blockIdx.x, t = threadIdx.x;
  int w = t>>6, lane = t&63;
  __shared__ float qL[512];
  __shared__ float attnL[4][8][68];
  __shared__ float UL[4][512];
  __shared__ float SL[4][8];
  qL[t]     = qbuf[b*512 + t];
  qL[t+256] = qbuf[b*512 + 256 + t];
  __syncthreads();

  int pos = chunk*CHUNK + w*64 + lane;          // one position per lane
  // phase 1: dots over 8 slots, softmax over slots (in-lane)
  const uint4* kr = (const uint4*)(kbf + ((long)b*N_ + pos)*64);
  float dots[8];
  #pragma unroll
  for (int i=0;i<8;++i) dots[i]=0.f;
  #pragma unroll
  for (int c=0;c<8;++c){
    uint4 kk = kr[c];
    float kf[8];
    kf[0]=bf_lo(kk.x); kf[1]=bf_hi(kk.x); kf[2]=bf_lo(kk.y); kf[3]=bf_hi(kk.y);
    kf[4]=bf_lo(kk.z); kf[5]=bf_hi(kk.z); kf[6]=bf_lo(kk.w); kf[7]=bf_hi(kk.w);
    #pragma unroll
    for (int i=0;i<8;++i){
      const float4 q0 = *(const float4*)&qL[i*64 + c*8];
      const float4 q1 = *(const float4*)&qL[i*64 + c*8 + 4];
      dots[i] += q0.x*kf[0]+q0.y*kf[1]+q0.z*kf[2]+q0.w*kf[3]
               + q1.x*kf[4]+q1.y*kf[5]+q1.z*kf[6]+q1.w*kf[7];
    }
  }
  float mx = dots[0]*SCALE_;
  #pragma unroll
  for (int i=1;i<8;++i) mx = fmaxf(mx, dots[i]*SCALE_);
  float e[8]; float sum=0.f;
  #pragma unroll
  for (int i=0;i<8;++i){ e[i] = __expf(dots[i]*SCALE_ - mx); sum += e[i]; }
  float isum = 1.f/sum;
  float attn[8];
  #pragma unroll
  for (int i=0;i<8;++i){ attn[i] = e[i]*isum + EPS_A; attnL[w][i][lane] = attn[i]; }
  #pragma unroll
  for (int i=0;i<8;++i){
    float sv = wsum64(attn[i]);
    if (lane==0) SL[w][i] = sv;
  }
  // phase 2: U[i][d] += attn[i][p] * v[p][d]   (lane = d; wave-private attnL, no barrier)
  int d = lane;
  const u16* vbase = vbf + ((long)b*N_ + chunk*CHUNK + w*64)*64 + d;
  float U[8];
  #pragma unroll
  for (int i=0;i<8;++i) U[i]=0.f;
  #pragma unroll 2
  for (int p0=0;p0<16;++p0){
    float vv0 = bf_lo((u32)vbase[(p0*4+0)*64]);
    float vv1 = bf_lo((u32)vbase[(p0*4+1)*64]);
    float vv2 = bf_lo((u32)vbase[(p0*4+2)*64]);
    float vv3 = bf_lo((u32)vbase[(p0*4+3)*64]);
    #pragma unroll
    for (int i=0;i<8;++i){
      const float4 a4 = *(const float4*)&attnL[w][i][p0*4];
      U[i] += a4.x*vv0 + a4.y*vv1 + a4.z*vv2 + a4.w*vv3;
    }
  }
  #pragma unroll
  for (int i=0;i<8;++i) UL[w][i*64+d] = U[i];
  __syncthreads();
  float s0 = UL[0][t]+UL[1][t]+UL[2][t]+UL[3][t];
  float s1 = UL[0][t+256]+UL[1][t+256]+UL[2][t+256]+UL[3][t+256];
  long pb = ((long)b*NCHUNK + chunk)*512;
  PU[pb + t]       = s0;
  PU[pb + t + 256] = s1;
  if (t < 8)
    PS[((long)b*NCHUNK + chunk)*8 + t] = SL[0][t]+SL[1][t]+SL[2][t]+SL[3][t];
}

// ---------------- reduce partials; GRU + LN + MLP; next q (or final out) ----------------
__global__ __launch_bounds__(512) void slot_update(
    const float* __restrict__ PU, const float* __restrict__ PS,
    float* __restrict__ slots,
    const float* __restrict__ WihT, const float* __restrict__ WhhT,
    const float* __restrict__ bih, const float* __restrict__ bhh,
    const float* __restrict__ W1, const float* __restrict__ b1,
    const float* __restrict__ W2, const float* __restrict__ b2,
    const float* __restrict__ lnffg, const float* __restrict__ lnffb,
    const float* __restrict__ lnsg, const float* __restrict__ lnsb,
    const float* __restrict__ Wq,
    float* __restrict__ qbuf, float* __restrict__ dout, int last){
  int b = blockIdx.x, t = threadIdx.x;
  int i = t>>6, d = t&63;
  __shared__ float updL[K_][68];
  __shared__ float spL[K_][68];
  __shared__ float sfL[K_][68];
  __shared__ float hL[K_][132];
  float u=0.f;
  #pragma unroll 4
  for (int c=0;c<NCHUNK;++c) u += PU[((long)b*NCHUNK + c)*512 + t];
  float S=0.f;
  #pragma unroll 4
  for (int c=0;c<NCHUNK;++c) S += PS[((long)b*NCHUNK + c)*8 + i];
  float upd = u / S;
  float sp  = slots[b*512 + t];
  updL[i][d] = upd;
  spL[i][d]  = sp;
  __syncthreads();
  float gx0 = bih[d], gx1 = bih[64+d], gx2 = bih[128+d];
  float gh0 = bhh[d], gh1 = bhh[64+d], gh2 = bhh[128+d];
  #pragma unroll 4
  for (int dd=0; dd<64; ++dd){
    float uv = updL[i][dd];
    float sv = spL[i][dd];
    const float* wi = WihT + dd*192 + d;
    const float* wh = WhhT + dd*192 + d;
    gx0 += uv*wi[0]; gx1 += uv*wi[64]; gx2 += uv*wi[128];
    gh0 += sv*wh[0]; gh1 += sv*wh[64]; gh2 += sv*wh[128];
  }
  float rg = 1.f/(1.f+__expf(-(gx0+gh0)));
  float zg = 1.f/(1.f+__expf(-(gx1+gh1)));
  float ng = tanhf(gx2 + rg*gh2);
  float sn = (1.f-zg)*ng + zg*sp;
  // LN_ff
  float m1 = wsum64(sn)*(1.f/64.f);
  float df = sn-m1;
  float vv = wsum64(df*df)*(1.f/64.f);
  float sf = df*rsqrtf(vv+EPS_LN)*lnffg[d] + lnffb[d];
  sfL[i][d] = sf;
  __syncthreads();
  // MLP
  float h0 = b1[d], h1 = b1[64+d];
  #pragma unroll 4
  for (int dd=0;dd<64;++dd){
    float sv = sfL[i][dd];
    h0 += sv*W1[dd*128 + d];
    h1 += sv*W1[dd*128 + 64 + d];
  }
  h0 = fmaxf(h0, 0.f); h1 = fmaxf(h1, 0.f);
  hL[i][d] = h0; hL[i][d+64] = h1;
  __syncthreads();
  float o = b2[d];
  #pragma unroll 4
  for (int hh=0; hh<128; ++hh) o += hL[i][hh]*W2[hh*64 + d];
  float out = sf + o;
  slots[b*512 + t] = out;
  if (last){
    dout[b*512 + t] = out;
  } else {
    float m2 = wsum64(out)*(1.f/64.f);
    float d2 = out-m2;
    float v2 = wsum64(d2*d2)*(1.f/64.f);
    float sq = d2*rsqrtf(v2+EPS_LN)*lnsg[d] + lnsb[d];
    updL[i][d] = sq;   // reuse (all reads of updL finished before sfL barrier)
    __syncthreads();
    float qv=0.f;
    #pragma unroll 8
    for (int dd=0;dd<64;++dd) qv += updL[i][dd]*Wq[dd*64 + d];
    qbuf[b*512 + t] = qv;
  }
}

extern "C" void kernel_launch(void* const* d_in, const int* in_sizes, int n_in,
                              void* d_out, int out_size, void* d_ws, size_t ws_size,
                              hipStream_t stream){
  const float* inp   = (const float*)d_in[0];
  const float* noise = (const float*)d_in[1];
  const float* mu    = (const float*)d_in[2];
  const float* sigma = (const float*)d_in[3];
  const float* Wq    = (const float*)d_in[4];
  const float* Wk    = (const float*)d_in[5];
  const float* Wv    = (const float*)d_in[6];
  const float* Wih   = (const float*)d_in[7];
  const float* Whh   = (const float*)d_in[8];
  const float* bih   = (const float*)d_in[9];
  const float* bhh   = (const float*)d_in[10];
  const float* W1    = (const float*)d_in[11];
  const float* b1    = (const float*)d_in[12];
  const float* W2    = (const float*)d_in[13];
  const float* b2    = (const float*)d_in[14];
  const float* lnig  = (const float*)d_in[15];
  const float* lnib  = (const float*)d_in[16];
  const float* lnsg  = (const float*)d_in[17];
  const float* lnsb  = (const float*)d_in[18];
  const float* lnffg = (const float*)d_in[19];
  const float* lnffb = (const float*)d_in[20];
  float* out = (float*)d_out;

  char* ws = (char*)d_ws;
  u16*   kbf   = (u16*)(ws);                       // 128*4096*64*2 = 67108864 B
  u16*   vbf   = (u16*)(ws + 67108864);            // 67108864 B
  float* qbuf  = (float*)(ws + 134217728);         // 262144 B
  float* slots = (float*)(ws + 134479872);         // 262144 B
  float* PU    = (float*)(ws + 134742016);         // 4194304 B
  float* PS    = (float*)(ws + 138936320);         // 65536 B
  float* WihT  = (float*)(ws + 139001856);         // 49152 B
  float* WhhT  = (float*)(ws + 139051008);         // 49152 B -> total ~139.1 MB

  prep_t<<<48,256,0,stream>>>(Wih, Whh, WihT, WhhT);
  slots_init<<<B_,512,0,stream>>>(noise, mu, sigma, Wq, lnsg, lnsb, slots, qbuf);
  kv_kernel<<<(B_*N_)/64,256,0,stream>>>(inp, Wk, Wv, lnig, lnib, kbf, vbf);
  for (int it=0; it<ITERS_; ++it){
    bigpass<<<dim3(NCHUNK,B_),256,0,stream>>>(kbf, vbf, qbuf, PU, PS);
    slot_update<<<B_,512,0,stream>>>(PU, PS, slots, WihT, WhhT, bih, bhh,
                                     W1, b1, W2, b2, lnffg, lnffb, lnsg, lnsb, Wq,
                                     qbuf, out, (it==ITERS_-1)?1:0);
  }
}

// Round 3
// 250.048 us; speedup vs baseline: 1.2880x; 1.2880x over previous
//
#include <hip/hip_runtime.h>
#include <hip/hip_bf16.h>

typedef unsigned int u32;
typedef unsigned short u16;
typedef __attribute__((ext_vector_type(8))) short short8;
typedef __attribute__((ext_vector_type(4))) float f32x4;

#define B_      128
#define N_      4096
#define D_      64
#define K_      8
#define H_      128
#define ITERS_  3
#define NCHUNK  16
#define CHUNK   256          // positions per bigpass block
#define SCALE_  0.125f
#define EPS_A   1e-8f
#define EPS_LN  1e-5f

__device__ __forceinline__ float bf_lo(u32 u){ union{u32 v; float f;} x; x.v = u<<16; return x.f; }
__device__ __forceinline__ float bf_hi(u32 u){ union{u32 v; float f;} x; x.v = u & 0xffff0000u; return x.f; }
__device__ __forceinline__ u16 f2bf(float f){
  union{float f; u32 v;} x; x.f = f;
  u32 v = x.v;
  return (u16)((v + 0x7fffu + ((v>>16)&1u))>>16);   // RNE
}
__device__ __forceinline__ float wsum64(float v){
  #pragma unroll
  for (int off=32; off; off>>=1) v += __shfl_xor(v, off, 64);
  return v;
}

// -------- one-time prep: transpose GRU weights; build bf16 [Wk|Wv]^T --------
__global__ void prep_t(const float* __restrict__ Wih, const float* __restrict__ Whh,
                       const float* __restrict__ Wk,  const float* __restrict__ Wv,
                       float* __restrict__ WihT, float* __restrict__ WhhT,
                       u16* __restrict__ WcT){
  int idx = blockIdx.x*256 + threadIdx.x;   // 48*256 = 12288
  if (idx < 192*64){
    int g = idx>>6, d = idx&63;
    WihT[d*192+g] = Wih[idx];
    WhhT[d*192+g] = Whh[idx];
  }
  if (idx < 128*64){
    int n = idx>>6, k = idx&63;            // WcT[n][k] = combined W column n
    float wv = (n<64) ? Wk[k*64+n] : Wv[k*64 + (n-64)];
    WcT[idx] = f2bf(wv);
  }
}

// ---------------- slots0 = mu + sigma*noise ; q0 = LN(slots0) @ Wq ----------------
__global__ __launch_bounds__(512) void slots_init(
    const float* __restrict__ noise, const float* __restrict__ mu, const float* __restrict__ sigma,
    const float* __restrict__ Wq, const float* __restrict__ lnsg, const float* __restrict__ lnsb,
    float* __restrict__ slots, float* __restrict__ qbuf){
  int b = blockIdx.x, t = threadIdx.x;
  int i = t>>6, d = t&63;
  __shared__ float svL[K_][68];
  float s0 = mu[d] + sigma[d]*noise[b*512 + t];
  slots[b*512 + t] = s0;
  float m  = wsum64(s0) * (1.f/64.f);
  float df = s0 - m;
  float vv = wsum64(df*df) * (1.f/64.f);
  float sv = df * rsqrtf(vv + EPS_LN) * lnsg[d] + lnsb[d];
  svL[i][d] = sv;
  __syncthreads();
  float acc = 0.f;
  #pragma unroll 8
  for (int dd=0; dd<64; ++dd) acc += svL[i][dd] * Wq[dd*64 + d];
  qbuf[b*512 + t] = acc;
}

// -------- x = LN(inputs); [k|v] = x_bf16 @ WcT^T via MFMA; bf16 out --------
__global__ __launch_bounds__(256) void kv_kernel(
    const float* __restrict__ inp, const u16* __restrict__ WcT,
    const float* __restrict__ lng, const float* __restrict__ lnb,
    u16* __restrict__ kout, u16* __restrict__ vout){
  __shared__ __align__(16) char smem[32768];   // [0,16K): x bf16 swz ; [16K,32K): W^T bf16 swz ; later: out tile
  int t = threadIdx.x;
  int lane = t&63, w = t>>6;

  // stage W^T (bf16 [n=128][k=64]) -> smem+16384, XOR-swizzled
  {
    const uint4* wg = (const uint4*)WcT;
    #pragma unroll
    for (int i=0;i<4;++i){
      int chunk = t + i*256;                 // 1024 chunks of 16B
      uint4 val = wg[chunk];
      int byte = chunk<<4;
      int sw = byte ^ (((byte>>7)&7)<<4);
      *(uint4*)(smem + 16384 + sw) = val;
    }
  }
  // load 128 x-rows (2 threads/row), LN fp32, pack bf16 -> smem swizzled
  long r0 = (long)blockIdx.x*128;
  int r = t>>1, h = t&1;
  {
    const float4* xr = (const float4*)(inp + (r0+r)*64 + h*32);
    float xv[32]; float s=0.f, sq=0.f;
    #pragma unroll
    for (int c=0;c<8;++c){
      float4 f = xr[c];
      xv[c*4+0]=f.x; xv[c*4+1]=f.y; xv[c*4+2]=f.z; xv[c*4+3]=f.w;
      s  += f.x+f.y+f.z+f.w;
      sq += f.x*f.x+f.y*f.y+f.z*f.z+f.w*f.w;
    }
    s  += __shfl_xor(s, 1, 64);
    sq += __shfl_xor(sq, 1, 64);
    float mean = s*(1.f/64.f);
    float inv  = rsqrtf(sq*(1.f/64.f) - mean*mean + EPS_LN);
    u32 pk[16];
    #pragma unroll
    for (int e=0;e<16;++e){
      int d0 = h*32 + e*2;
      float a0 = (xv[e*2]  -mean)*inv*lng[d0]   + lnb[d0];
      float a1 = (xv[e*2+1]-mean)*inv*lng[d0+1] + lnb[d0+1];
      pk[e] = (u32)f2bf(a0) | ((u32)f2bf(a1)<<16);
    }
    #pragma unroll
    for (int c=0;c<4;++c){
      uint4 val; val.x=pk[c*4]; val.y=pk[c*4+1]; val.z=pk[c*4+2]; val.w=pk[c*4+3];
      int byte = r*128 + h*64 + c*16;
      int sw = byte ^ ((r&7)<<4);
      *(uint4*)(smem + sw) = val;
    }
  }
  __syncthreads();

  // MFMA: wave w owns rows [w*32, w*32+32) x all 128 cols
  f32x4 acc[2][8];
  #pragma unroll
  for (int mt=0;mt<2;++mt){
    #pragma unroll
    for (int nt=0;nt<8;++nt) acc[mt][nt] = (f32x4){0.f,0.f,0.f,0.f};
  }
  int fr = lane&15, fq = lane>>4;
  #pragma unroll
  for (int kk=0; kk<2; ++kk){
    short8 a[2], b[8];
    #pragma unroll
    for (int mt=0; mt<2; ++mt){
      int row = w*32 + mt*16 + fr;
      int byte = row*128 + kk*64 + fq*16;
      a[mt] = *(const short8*)(smem + (byte ^ ((row&7)<<4)));
    }
    #pragma unroll
    for (int nt=0; nt<8; ++nt){
      int n = nt*16 + fr;
      int byte = n*128 + kk*64 + fq*16;
      b[nt] = *(const short8*)(smem + 16384 + (byte ^ ((n&7)<<4)));
    }
    #pragma unroll
    for (int mt=0; mt<2; ++mt){
      #pragma unroll
      for (int nt=0; nt<8; ++nt)
        acc[mt][nt] = __builtin_amdgcn_mfma_f32_16x16x32_bf16(a[mt], b[nt], acc[mt][nt], 0, 0, 0);
    }
  }
  __syncthreads();   // xs/ws reads done; reuse smem as out tile [128][128] u16

  u16* outs = (u16*)smem;
  #pragma unroll
  for (int mt=0; mt<2; ++mt){
    int rowb = w*32 + mt*16 + fq*4;
    #pragma unroll
    for (int nt=0; nt<8; ++nt){
      int col = nt*16 + fr;
      #pragma unroll
      for (int i=0;i<4;++i)
        outs[(rowb+i)*128 + col] = f2bf(acc[mt][nt][i]);
    }
  }
  __syncthreads();
  uint4* kp = (uint4*)kout; uint4* vp = (uint4*)vout;
  const uint4* o4 = (const uint4*)smem;
  #pragma unroll
  for (int i=0;i<8;++i){
    int flat = t + i*256;
    int rr = flat>>4, c = flat&15;
    uint4 val = o4[flat];
    long grow = r0 + rr;
    if (c<8) kp[grow*8 + c]     = val;
    else     vp[grow*8 + (c-8)] = val;
  }
}

// ---------------- fused dots/softmax-over-K/partial S,U per (b,chunk) ----------------
__global__ __launch_bounds__(256) void bigpass(
    const u16* __restrict__ kbf, const u16* __restrict__ vbf,
    const float* __restrict__ qbuf,
    float* __restrict__ PU, float* __restrict__ PS){
  int b = blockIdx.y, chunk = blockIdx.x, t = threadIdx.x;
  int w = t>>6, lane = t&63;
  __shared__ float qL[512];
  __shared__ float attnL[4][8][68];
  __shared__ float UL[4][512];
  __shared__ float SL[4][8];
  qL[t]     = qbuf[b*512 + t];
  qL[t+256] = qbuf[b*512 + 256 + t];
  __syncthreads();

  int pos = chunk*CHUNK + w*64 + lane;          // one position per lane
  // phase 1: dots over 8 slots, softmax over slots (in-lane)
  const uint4* kr = (const uint4*)(kbf + ((long)b*N_ + pos)*64);
  float dots[8];
  #pragma unroll
  for (int i=0;i<8;++i) dots[i]=0.f;
  #pragma unroll
  for (int c=0;c<8;++c){
    uint4 kk = kr[c];
    float kf[8];
    kf[0]=bf_lo(kk.x); kf[1]=bf_hi(kk.x); kf[2]=bf_lo(kk.y); kf[3]=bf_hi(kk.y);
    kf[4]=bf_lo(kk.z); kf[5]=bf_hi(kk.z); kf[6]=bf_lo(kk.w); kf[7]=bf_hi(kk.w);
    #pragma unroll
    for (int i=0;i<8;++i){
      const float4 q0 = *(const float4*)&qL[i*64 + c*8];
      const float4 q1 = *(const float4*)&qL[i*64 + c*8 + 4];
      dots[i] += q0.x*kf[0]+q0.y*kf[1]+q0.z*kf[2]+q0.w*kf[3]
               + q1.x*kf[4]+q1.y*kf[5]+q1.z*kf[6]+q1.w*kf[7];
    }
  }
  float mx = dots[0]*SCALE_;
  #pragma unroll
  for (int i=1;i<8;++i) mx = fmaxf(mx, dots[i]*SCALE_);
  float e[8]; float sum=0.f;
  #pragma unroll
  for (int i=0;i<8;++i){ e[i] = __expf(dots[i]*SCALE_ - mx); sum += e[i]; }
  float isum = 1.f/sum;
  float attn[8];
  #pragma unroll
  for (int i=0;i<8;++i){ attn[i] = e[i]*isum + EPS_A; attnL[w][i][lane] = attn[i]; }
  #pragma unroll
  for (int i=0;i<8;++i){
    float sv = wsum64(attn[i]);
    if (lane==0) SL[w][i] = sv;
  }
  // phase 2: U[i][d] += attn[i][p] * v[p][d]   (lane = d; wave-private attnL, no barrier)
  int d = lane;
  const u16* vbase = vbf + ((long)b*N_ + chunk*CHUNK + w*64)*64 + d;
  float U[8];
  #pragma unroll
  for (int i=0;i<8;++i) U[i]=0.f;
  #pragma unroll 2
  for (int p0=0;p0<16;++p0){
    float vv0 = bf_lo((u32)vbase[(p0*4+0)*64]);
    float vv1 = bf_lo((u32)vbase[(p0*4+1)*64]);
    float vv2 = bf_lo((u32)vbase[(p0*4+2)*64]);
    float vv3 = bf_lo((u32)vbase[(p0*4+3)*64]);
    #pragma unroll
    for (int i=0;i<8;++i){
      const float4 a4 = *(const float4*)&attnL[w][i][p0*4];
      U[i] += a4.x*vv0 + a4.y*vv1 + a4.z*vv2 + a4.w*vv3;
    }
  }
  #pragma unroll
  for (int i=0;i<8;++i) UL[w][i*64+d] = U[i];
  __syncthreads();
  float s0 = UL[0][t]+UL[1][t]+UL[2][t]+UL[3][t];
  float s1 = UL[0][t+256]+UL[1][t+256]+UL[2][t+256]+UL[3][t+256];
  long pb = ((long)b*NCHUNK + chunk)*512;
  PU[pb + t]       = s0;
  PU[pb + t + 256] = s1;
  if (t < 8)
    PS[((long)b*NCHUNK + chunk)*8 + t] = SL[0][t]+SL[1][t]+SL[2][t]+SL[3][t];
}

// ---------------- reduce partials; GRU + LN + MLP; next q (or final out) ----------------
__global__ __launch_bounds__(512) void slot_update(
    const float* __restrict__ PU, const float* __restrict__ PS,
    float* __restrict__ slots,
    const float* __restrict__ WihT, const float* __restrict__ WhhT,
    const float* __restrict__ bih, const float* __restrict__ bhh,
    const float* __restrict__ W1, const float* __restrict__ b1,
    const float* __restrict__ W2, const float* __restrict__ b2,
    const float* __restrict__ lnffg, const float* __restrict__ lnffb,
    const float* __restrict__ lnsg, const float* __restrict__ lnsb,
    const float* __restrict__ Wq,
    float* __restrict__ qbuf, float* __restrict__ dout, int last){
  int b = blockIdx.x, t = threadIdx.x;
  int i = t>>6, d = t&63;
  __shared__ float updL[K_][68];
  __shared__ float spL[K_][68];
  __shared__ float sfL[K_][68];
  __shared__ float hL[K_][132];
  float u=0.f;
  #pragma unroll 4
  for (int c=0;c<NCHUNK;++c) u += PU[((long)b*NCHUNK + c)*512 + t];
  float S=0.f;
  #pragma unroll 4
  for (int c=0;c<NCHUNK;++c) S += PS[((long)b*NCHUNK + c)*8 + i];
  float upd = u / S;
  float sp  = slots[b*512 + t];
  updL[i][d] = upd;
  spL[i][d]  = sp;
  __syncthreads();
  float gx0 = bih[d], gx1 = bih[64+d], gx2 = bih[128+d];
  float gh0 = bhh[d], gh1 = bhh[64+d], gh2 = bhh[128+d];
  #pragma unroll 4
  for (int dd=0; dd<64; ++dd){
    float uv = updL[i][dd];
    float sv = spL[i][dd];
    const float* wi = WihT + dd*192 + d;
    const float* wh = WhhT + dd*192 + d;
    gx0 += uv*wi[0]; gx1 += uv*wi[64]; gx2 += uv*wi[128];
    gh0 += sv*wh[0]; gh1 += sv*wh[64]; gh2 += sv*wh[128];
  }
  float rg = 1.f/(1.f+__expf(-(gx0+gh0)));
  float zg = 1.f/(1.f+__expf(-(gx1+gh1)));
  float ng = tanhf(gx2 + rg*gh2);
  float sn = (1.f-zg)*ng + zg*sp;
  // LN_ff
  float m1 = wsum64(sn)*(1.f/64.f);
  float df = sn-m1;
  float vv = wsum64(df*df)*(1.f/64.f);
  float sf = df*rsqrtf(vv+EPS_LN)*lnffg[d] + lnffb[d];
  sfL[i][d] = sf;
  __syncthreads();
  // MLP
  float h0 = b1[d], h1 = b1[64+d];
  #pragma unroll 4
  for (int dd=0;dd<64;++dd){
    float sv = sfL[i][dd];
    h0 += sv*W1[dd*128 + d];
    h1 += sv*W1[dd*128 + 64 + d];
  }
  h0 = fmaxf(h0, 0.f); h1 = fmaxf(h1, 0.f);
  hL[i][d] = h0; hL[i][d+64] = h1;
  __syncthreads();
  float o = b2[d];
  #pragma unroll 4
  for (int hh=0; hh<128; ++hh) o += hL[i][hh]*W2[hh*64 + d];
  float out = sf + o;
  slots[b*512 + t] = out;
  if (last){
    dout[b*512 + t] = out;
  } else {
    float m2 = wsum64(out)*(1.f/64.f);
    float d2 = out-m2;
    float v2 = wsum64(d2*d2)*(1.f/64.f);
    float sq = d2*rsqrtf(v2+EPS_LN)*lnsg[d] + lnsb[d];
    updL[i][d] = sq;   // reuse (all reads of updL finished before sfL barrier)
    __syncthreads();
    float qv=0.f;
    #pragma unroll 8
    for (int dd=0;dd<64;++dd) qv += updL[i][dd]*Wq[dd*64 + d];
    qbuf[b*512 + t] = qv;
  }
}

extern "C" void kernel_launch(void* const* d_in, const int* in_sizes, int n_in,
                              void* d_out, int out_size, void* d_ws, size_t ws_size,
                              hipStream_t stream){
  const float* inp   = (const float*)d_in[0];
  const float* noise = (const float*)d_in[1];
  const float* mu    = (const float*)d_in[2];
  const float* sigma = (const float*)d_in[3];
  const float* Wq    = (const float*)d_in[4];
  const float* Wk    = (const float*)d_in[5];
  const float* Wv    = (const float*)d_in[6];
  const float* Wih   = (const float*)d_in[7];
  const float* Whh   = (const float*)d_in[8];
  const float* bih   = (const float*)d_in[9];
  const float* bhh   = (const float*)d_in[10];
  const float* W1    = (const float*)d_in[11];
  const float* b1    = (const float*)d_in[12];
  const float* W2    = (const float*)d_in[13];
  const float* b2    = (const float*)d_in[14];
  const float* lnig  = (const float*)d_in[15];
  const float* lnib  = (const float*)d_in[16];
  const float* lnsg  = (const float*)d_in[17];
  const float* lnsb  = (const float*)d_in[18];
  const float* lnffg = (const float*)d_in[19];
  const float* lnffb = (const float*)d_in[20];
  float* out = (float*)d_out;

  char* ws = (char*)d_ws;
  u16*   kbf   = (u16*)(ws);                       // 67108864 B
  u16*   vbf   = (u16*)(ws + 67108864);            // 67108864 B
  float* qbuf  = (float*)(ws + 134217728);         // 262144 B
  float* slots = (float*)(ws + 134479872);         // 262144 B
  float* PU    = (float*)(ws + 134742016);         // 4194304 B
  float* PS    = (float*)(ws + 138936320);         // 65536 B
  float* WihT  = (float*)(ws + 139001856);         // 49152 B
  float* WhhT  = (float*)(ws + 139051008);         // 49152 B
  // WcT (16 KB) aliases the START of PU: only read by kv_kernel, which runs
  // before the first bigpass write to PU. Stream-ordered, deterministic.
  u16*   WcT   = (u16*)(ws + 134742016);

  prep_t<<<48,256,0,stream>>>(Wih, Whh, Wk, Wv, WihT, WhhT, WcT);
  slots_init<<<B_,512,0,stream>>>(noise, mu, sigma, Wq, lnsg, lnsb, slots, qbuf);
  kv_kernel<<<(B_*N_)/128,256,0,stream>>>(inp, WcT, lnig, lnib, kbf, vbf);
  for (int it=0; it<ITERS_; ++it){
    bigpass<<<dim3(NCHUNK,B_),256,0,stream>>>(kbf, vbf, qbuf, PU, PS);
    slot_update<<<B_,512,0,stream>>>(PU, PS, slots, WihT, WhhT, bih, bhh,
                                     W1, b1, W2, b2, lnffg, lnffb, lnsg, lnsb, Wq,
                                     qbuf, out, (it==ITERS_-1)?1:0);
  }
}

// Round 4
// 246.398 us; speedup vs baseline: 1.3070x; 1.0148x over previous
//
#include <hip/hip_runtime.h>
#include <hip/hip_bf16.h>

typedef unsigned int u32;
typedef unsigned short u16;

#define B_      128
#define N_      4096
#define D_      64
#define K_      8
#define H_      128
#define ITERS_  3
#define NCHUNK  16
#define CHUNK   256
#define SCALE_  0.125f
#define EPS_A   1e-8f
#define EPS_LN  1e-5f

__device__ __forceinline__ float bf_lo(u32 u){ union{u32 v; float f;} x; x.v = u<<16; return x.f; }
__device__ __forceinline__ float bf_hi(u32 u){ union{u32 v; float f;} x; x.v = u & 0xffff0000u; return x.f; }
__device__ __forceinline__ u16 f2bf(float f){
  union{float f; u32 v;} x; x.f = f;
  u32 v = x.v;
  return (u16)((v + 0x7fffu + ((v>>16)&1u))>>16);   // RNE
}
__device__ __forceinline__ float wsum64(float v){
  #pragma unroll
  for (int off=32; off; off>>=1) v += __shfl_xor(v, off, 64);
  return v;
}

// ---- one-time prep: transpose GRU weights; WkT2[dd][d] = Wk[d][dd] ----
__global__ void prep_t(const float* __restrict__ Wih, const float* __restrict__ Whh,
                       const float* __restrict__ Wk,
                       float* __restrict__ WihT, float* __restrict__ WhhT,
                       float* __restrict__ WkT2){
  int idx = blockIdx.x*256 + threadIdx.x;   // 48*256 = 12288
  if (idx < 192*64){
    int g = idx>>6, d = idx&63;
    WihT[d*192+g] = Wih[idx];
    WhhT[d*192+g] = Whh[idx];
  }
  if (idx < 4096){
    int dd = idx>>6, d = idx&63;
    WkT2[idx] = Wk[d*64+dd];
  }
}

// ---- slots0 = mu + sigma*noise ; q = LN(slots0)@Wq ; qt = q@Wk^T ----
__global__ __launch_bounds__(512) void slots_init(
    const float* __restrict__ noise, const float* __restrict__ mu, const float* __restrict__ sigma,
    const float* __restrict__ Wq, const float* __restrict__ WkT2,
    const float* __restrict__ lnsg, const float* __restrict__ lnsb,
    float* __restrict__ slots, float* __restrict__ qbuf){
  int b = blockIdx.x, t = threadIdx.x;
  int i = t>>6, d = t&63;
  __shared__ float svL[K_][68];
  float s0 = mu[d] + sigma[d]*noise[b*512 + t];
  slots[b*512 + t] = s0;
  float m  = wsum64(s0) * (1.f/64.f);
  float df = s0 - m;
  float vv = wsum64(df*df) * (1.f/64.f);
  float sv = df * rsqrtf(vv + EPS_LN) * lnsg[d] + lnsb[d];
  svL[i][d] = sv;
  __syncthreads();
  float q = 0.f;
  #pragma unroll 8
  for (int dd=0; dd<64; ++dd) q += svL[i][dd] * Wq[dd*64 + d];
  __syncthreads();
  svL[i][d] = q;
  __syncthreads();
  float qt = 0.f;
  #pragma unroll 8
  for (int dd=0; dd<64; ++dd) qt += svL[i][dd] * WkT2[dd*64 + d];
  qbuf[b*512 + t] = qt;
}

// ---- xhat = LN(inputs) as bf16 : pure streaming ----
__global__ __launch_bounds__(256) void ln_kernel(
    const float* __restrict__ inp, const float* __restrict__ lng, const float* __restrict__ lnb,
    u16* __restrict__ xhat){
  long r0 = (long)blockIdx.x*128;
  int t = threadIdx.x;
  int r = t>>1, h = t&1;
  const float4* xr = (const float4*)(inp + (r0+r)*64 + h*32);
  float xv[32]; float s=0.f, sq=0.f;
  #pragma unroll
  for (int c=0;c<8;++c){
    float4 f = xr[c];
    xv[c*4+0]=f.x; xv[c*4+1]=f.y; xv[c*4+2]=f.z; xv[c*4+3]=f.w;
    s  += f.x+f.y+f.z+f.w;
    sq += f.x*f.x+f.y*f.y+f.z*f.z+f.w*f.w;
  }
  s  += __shfl_xor(s, 1, 64);
  sq += __shfl_xor(sq, 1, 64);
  float mean = s*(1.f/64.f);
  float inv  = rsqrtf(sq*(1.f/64.f) - mean*mean + EPS_LN);
  uint4* orow = (uint4*)(xhat + (r0+r)*64);
  #pragma unroll
  for (int c=0;c<4;++c){
    u32 pk[4];
    #pragma unroll
    for (int e=0;e<4;++e){
      int d0 = h*32 + c*8 + e*2;
      float a0 = (xv[c*8+e*2]  -mean)*inv*lng[d0]   + lnb[d0];
      float a1 = (xv[c*8+e*2+1]-mean)*inv*lng[d0+1] + lnb[d0+1];
      pk[e] = (u32)f2bf(a0) | ((u32)f2bf(a1)<<16);
    }
    uint4 val; val.x=pk[0]; val.y=pk[1]; val.z=pk[2]; val.w=pk[3];
    orow[h*4 + c] = val;
  }
}

// ---- fused dots/softmax-over-K/partial S,U over xhat, per (b,chunk) ----
__global__ __launch_bounds__(256) void bigpass(
    const u16* __restrict__ xhat, const float* __restrict__ qbuf,
    float* __restrict__ PU, float* __restrict__ PS){
  int b = blockIdx.y, chunk = blockIdx.x, t = threadIdx.x;
  int w = t>>6, lane = t&63;
  __shared__ __align__(16) u16 xt[4*64*64];     // 32 KB, XOR-swizzled rows
  __shared__ float qL[512];
  __shared__ float attnT[4][64][8];             // [wave][pos][slot]
  __shared__ float UL[4][512];
  __shared__ float SL[4][8];
  qL[t]     = qbuf[b*512 + t];
  qL[t+256] = qbuf[b*512 + 256 + t];
  // stage 256 rows x 64 bf16 (32 KB), swizzle: byte ^= ((row&7)<<4)
  const uint4* gsrc = (const uint4*)(xhat + ((long)b*N_ + (long)chunk*CHUNK)*64);
  #pragma unroll
  for (int c=0;c<8;++c){
    int ch = c*256 + t;
    uint4 val = gsrc[ch];
    int row = ch>>3;
    int byte = (ch*16) ^ ((row&7)<<4);
    *(uint4*)((char*)xt + byte) = val;
  }
  __syncthreads();

  // phase 1: lane = position; dots over 8 slots from LDS rows
  int rowt = w*64 + lane;
  float dots[8];
  #pragma unroll
  for (int i=0;i<8;++i) dots[i]=0.f;
  #pragma unroll
  for (int c=0;c<8;++c){
    int byte = (rowt*128 + c*16) ^ ((rowt&7)<<4);
    uint4 kk = *(const uint4*)((char*)xt + byte);
    float kf[8];
    kf[0]=bf_lo(kk.x); kf[1]=bf_hi(kk.x); kf[2]=bf_lo(kk.y); kf[3]=bf_hi(kk.y);
    kf[4]=bf_lo(kk.z); kf[5]=bf_hi(kk.z); kf[6]=bf_lo(kk.w); kf[7]=bf_hi(kk.w);
    #pragma unroll
    for (int i=0;i<8;++i){
      const float4 q0 = *(const float4*)&qL[i*64 + c*8];
      const float4 q1 = *(const float4*)&qL[i*64 + c*8 + 4];
      dots[i] += q0.x*kf[0]+q0.y*kf[1]+q0.z*kf[2]+q0.w*kf[3]
               + q1.x*kf[4]+q1.y*kf[5]+q1.z*kf[6]+q1.w*kf[7];
    }
  }
  float mx = dots[0]*SCALE_;
  #pragma unroll
  for (int i=1;i<8;++i) mx = fmaxf(mx, dots[i]*SCALE_);
  float e[8]; float sum=0.f;
  #pragma unroll
  for (int i=0;i<8;++i){ e[i] = __expf(dots[i]*SCALE_ - mx); sum += e[i]; }
  float isum = 1.f/sum;
  float attn[8];
  #pragma unroll
  for (int i=0;i<8;++i) attn[i] = e[i]*isum + EPS_A;
  { float4 a0, a1;
    a0.x=attn[0]; a0.y=attn[1]; a0.z=attn[2]; a0.w=attn[3];
    a1.x=attn[4]; a1.y=attn[5]; a1.z=attn[6]; a1.w=attn[7];
    *(float4*)&attnT[w][lane][0] = a0;
    *(float4*)&attnT[w][lane][4] = a1;
  }
  #pragma unroll
  for (int i=0;i<8;++i){
    float sv = wsum64(attn[i]);
    if (lane==0) SL[w][i] = sv;
  }
  // phase 2: lane = d; column reads from swizzled LDS tile (wave-private, no barrier)
  float U[8];
  #pragma unroll
  for (int i=0;i<8;++i) U[i]=0.f;
  #pragma unroll 4
  for (int pp=0; pp<64; ++pp){
    int rt = w*64 + pp;
    int byte = (rt*128 + lane*2) ^ ((rt&7)<<4);
    float xv = bf_lo((u32)*(const u16*)((char*)xt + byte));
    float4 a0 = *(const float4*)&attnT[w][pp][0];
    float4 a1 = *(const float4*)&attnT[w][pp][4];
    U[0] += a0.x*xv; U[1] += a0.y*xv; U[2] += a0.z*xv; U[3] += a0.w*xv;
    U[4] += a1.x*xv; U[5] += a1.y*xv; U[6] += a1.z*xv; U[7] += a1.w*xv;
  }
  #pragma unroll
  for (int i=0;i<8;++i) UL[w][i*64+lane] = U[i];
  __syncthreads();
  float s0 = UL[0][t]+UL[1][t]+UL[2][t]+UL[3][t];
  float s1 = UL[0][t+256]+UL[1][t+256]+UL[2][t+256]+UL[3][t+256];
  long pb = ((long)b*NCHUNK + chunk)*512;
  PU[pb + t]       = s0;
  PU[pb + t + 256] = s1;
  if (t < 8)
    PS[((long)b*NCHUNK + chunk)*8 + t] = SL[0][t]+SL[1][t]+SL[2][t]+SL[3][t];
}

// ---- reduce partials; updates = (U/S)@Wv; GRU + LN + MLP; next q-tilde ----
__global__ __launch_bounds__(512) void slot_update(
    const float* __restrict__ PU, const float* __restrict__ PS,
    float* __restrict__ slots,
    const float* __restrict__ WihT, const float* __restrict__ WhhT,
    const float* __restrict__ bih, const float* __restrict__ bhh,
    const float* __restrict__ W1, const float* __restrict__ b1,
    const float* __restrict__ W2, const float* __restrict__ b2,
    const float* __restrict__ lnffg, const float* __restrict__ lnffb,
    const float* __restrict__ lnsg, const float* __restrict__ lnsb,
    const float* __restrict__ Wq, const float* __restrict__ Wv,
    const float* __restrict__ WkT2,
    float* __restrict__ qbuf, float* __restrict__ dout, int last){
  int b = blockIdx.x, t = threadIdx.x;
  int i = t>>6, d = t&63;
  __shared__ float updL[K_][68];
  __shared__ float spL[K_][68];
  __shared__ float sfL[K_][68];
  __shared__ float hL[K_][132];
  float u=0.f;
  #pragma unroll 4
  for (int c=0;c<NCHUNK;++c) u += PU[((long)b*NCHUNK + c)*512 + t];
  float S=0.f;
  #pragma unroll 4
  for (int c=0;c<NCHUNK;++c) S += PS[((long)b*NCHUNK + c)*8 + i];
  float ut = u / S;                       // Utilde[i][d]
  float sp = slots[b*512 + t];
  sfL[i][d] = ut;
  spL[i][d] = sp;
  __syncthreads();
  float upd = 0.f;                        // updates = Utilde @ Wv
  #pragma unroll 4
  for (int dd=0; dd<64; ++dd) upd += sfL[i][dd]*Wv[dd*64 + d];
  updL[i][d] = upd;
  __syncthreads();
  float gx0 = bih[d], gx1 = bih[64+d], gx2 = bih[128+d];
  float gh0 = bhh[d], gh1 = bhh[64+d], gh2 = bhh[128+d];
  #pragma unroll 4
  for (int dd=0; dd<64; ++dd){
    float uv = updL[i][dd];
    float sv = spL[i][dd];
    const float* wi = WihT + dd*192 + d;
    const float* wh = WhhT + dd*192 + d;
    gx0 += uv*wi[0]; gx1 += uv*wi[64]; gx2 += uv*wi[128];
    gh0 += sv*wh[0]; gh1 += sv*wh[64]; gh2 += sv*wh[128];
  }
  float rg = 1.f/(1.f+__expf(-(gx0+gh0)));
  float zg = 1.f/(1.f+__expf(-(gx1+gh1)));
  float ng = tanhf(gx2 + rg*gh2);
  float sn = (1.f-zg)*ng + zg*sp;
  // LN_ff
  float m1 = wsum64(sn)*(1.f/64.f);
  float df = sn-m1;
  float vv = wsum64(df*df)*(1.f/64.f);
  float sf = df*rsqrtf(vv+EPS_LN)*lnffg[d] + lnffb[d];
  sfL[i][d] = sf;
  __syncthreads();
  // MLP
  float h0 = b1[d], h1 = b1[64+d];
  #pragma unroll 4
  for (int dd=0;dd<64;++dd){
    float sv = sfL[i][dd];
    h0 += sv*W1[dd*128 + d];
    h1 += sv*W1[dd*128 + 64 + d];
  }
  h0 = fmaxf(h0, 0.f); h1 = fmaxf(h1, 0.f);
  hL[i][d] = h0; hL[i][d+64] = h1;
  __syncthreads();
  float o = b2[d];
  #pragma unroll 4
  for (int hh=0; hh<128; ++hh) o += hL[i][hh]*W2[hh*64 + d];
  float out = sf + o;
  slots[b*512 + t] = out;
  if (last){
    dout[b*512 + t] = out;
  } else {
    float m2 = wsum64(out)*(1.f/64.f);
    float d2 = out-m2;
    float v2 = wsum64(d2*d2)*(1.f/64.f);
    float sq = d2*rsqrtf(v2+EPS_LN)*lnsg[d] + lnsb[d];
    updL[i][d] = sq;
    __syncthreads();
    float qv=0.f;
    #pragma unroll 8
    for (int dd=0;dd<64;++dd) qv += updL[i][dd]*Wq[dd*64 + d];
    __syncthreads();
    updL[i][d] = qv;
    __syncthreads();
    float qt=0.f;
    #pragma unroll 8
    for (int dd=0;dd<64;++dd) qt += updL[i][dd]*WkT2[dd*64 + d];
    qbuf[b*512 + t] = qt;
  }
}

extern "C" void kernel_launch(void* const* d_in, const int* in_sizes, int n_in,
                              void* d_out, int out_size, void* d_ws, size_t ws_size,
                              hipStream_t stream){
  const float* inp   = (const float*)d_in[0];
  const float* noise = (const float*)d_in[1];
  const float* mu    = (const float*)d_in[2];
  const float* sigma = (const float*)d_in[3];
  const float* Wq    = (const float*)d_in[4];
  const float* Wk    = (const float*)d_in[5];
  const float* Wv    = (const float*)d_in[6];
  const float* Wih   = (const float*)d_in[7];
  const float* Whh   = (const float*)d_in[8];
  const float* bih   = (const float*)d_in[9];
  const float* bhh   = (const float*)d_in[10];
  const float* W1    = (const float*)d_in[11];
  const float* b1    = (const float*)d_in[12];
  const float* W2    = (const float*)d_in[13];
  const float* b2    = (const float*)d_in[14];
  const float* lnig  = (const float*)d_in[15];
  const float* lnib  = (const float*)d_in[16];
  const float* lnsg  = (const float*)d_in[17];
  const float* lnsb  = (const float*)d_in[18];
  const float* lnffg = (const float*)d_in[19];
  const float* lnffb = (const float*)d_in[20];
  float* out = (float*)d_out;

  char* ws = (char*)d_ws;
  u16*   xhat  = (u16*)(ws);                       // 128*4096*64*2 = 67108864 B
  float* qbuf  = (float*)(ws + 67108864);          // 262144 B
  float* slots = (float*)(ws + 67371008);          // 262144 B
  float* PU    = (float*)(ws + 67633152);          // 4194304 B
  float* PS    = (float*)(ws + 71827456);          // 65536 B
  float* WihT  = (float*)(ws + 71892992);          // 49152 B
  float* WhhT  = (float*)(ws + 71942144);          // 49152 B
  float* WkT2  = (float*)(ws + 71991296);          // 16384 B -> ~72 MB total

  prep_t<<<48,256,0,stream>>>(Wih, Whh, Wk, WihT, WhhT, WkT2);
  slots_init<<<B_,512,0,stream>>>(noise, mu, sigma, Wq, WkT2, lnsg, lnsb, slots, qbuf);
  ln_kernel<<<(B_*N_)/128,256,0,stream>>>(inp, lnig, lnib, xhat);
  for (int it=0; it<ITERS_; ++it){
    bigpass<<<dim3(NCHUNK,B_),256,0,stream>>>(xhat, qbuf, PU, PS);
    slot_update<<<B_,512,0,stream>>>(PU, PS, slots, WihT, WhhT, bih, bhh,
                                     W1, b1, W2, b2, lnffg, lnffb, lnsg, lnsb,
                                     Wq, Wv, WkT2, qbuf, out, (it==ITERS_-1)?1:0);
  }
}

// Round 5
// 197.241 us; speedup vs baseline: 1.6328x; 1.2492x over previous
//
#include <hip/hip_runtime.h>
#include <hip/hip_bf16.h>

typedef unsigned int u32;
typedef unsigned short u16;
typedef __attribute__((ext_vector_type(8))) short short8;
typedef __attribute__((ext_vector_type(4))) float f32x4;

#define B_      128
#define N_      4096
#define D_      64
#define K_      8
#define H_      128
#define ITERS_  3
#define NCHUNK  16
#define CHUNK   256
#define SCALE_  0.125f
#define EPS_A   1e-8f
#define EPS_LN  1e-5f

__device__ __forceinline__ float bf_lo(u32 u){ union{u32 v; float f;} x; x.v = u<<16; return x.f; }
__device__ __forceinline__ u16 f2bf(float f){
  union{float f; u32 v;} x; x.f = f;
  u32 v = x.v;
  return (u16)((v + 0x7fffu + ((v>>16)&1u))>>16);   // RNE
}
__device__ __forceinline__ float wsum64(float v){
  #pragma unroll
  for (int off=32; off; off>>=1) v += __shfl_xor(v, off, 64);
  return v;
}

// ---- one-time prep: transpose GRU weights; WkT2[dd][d] = Wk[d][dd] ----
__global__ void prep_t(const float* __restrict__ Wih, const float* __restrict__ Whh,
                       const float* __restrict__ Wk,
                       float* __restrict__ WihT, float* __restrict__ WhhT,
                       float* __restrict__ WkT2){
  int idx = blockIdx.x*256 + threadIdx.x;   // 48*256 = 12288
  if (idx < 192*64){
    int g = idx>>6, d = idx&63;
    WihT[d*192+g] = Wih[idx];
    WhhT[d*192+g] = Whh[idx];
  }
  if (idx < 4096){
    int dd = idx>>6, d = idx&63;
    WkT2[idx] = Wk[d*64+dd];
  }
}

// ---- slots0 = mu + sigma*noise ; q = LN(slots0)@Wq ; qt = q@Wk^T (bf16, padded 16 rows) ----
__global__ __launch_bounds__(512) void slots_init(
    const float* __restrict__ noise, const float* __restrict__ mu, const float* __restrict__ sigma,
    const float* __restrict__ Wq, const float* __restrict__ WkT2,
    const float* __restrict__ lnsg, const float* __restrict__ lnsb,
    float* __restrict__ slots, u16* __restrict__ qbuf16){
  int b = blockIdx.x, t = threadIdx.x;
  int i = t>>6, d = t&63;
  __shared__ float svL[K_][68];
  float s0 = mu[d] + sigma[d]*noise[b*512 + t];
  slots[b*512 + t] = s0;
  float m  = wsum64(s0) * (1.f/64.f);
  float df = s0 - m;
  float vv = wsum64(df*df) * (1.f/64.f);
  float sv = df * rsqrtf(vv + EPS_LN) * lnsg[d] + lnsb[d];
  svL[i][d] = sv;
  __syncthreads();
  float q = 0.f;
  #pragma unroll 8
  for (int dd=0; dd<64; ++dd) q += svL[i][dd] * Wq[dd*64 + d];
  __syncthreads();
  svL[i][d] = q;
  __syncthreads();
  float qt = 0.f;
  #pragma unroll 8
  for (int dd=0; dd<64; ++dd) qt += svL[i][dd] * WkT2[dd*64 + d];
  qbuf16[b*1024 + t] = f2bf(qt);
  qbuf16[b*1024 + 512 + t] = 0;          // pad rows 8..15
}

// ---- fused: (iter0) LN + dots(MFMA) + softmax-over-K + partial S,U ----
template<int FUSED>
__global__ __launch_bounds__(256) void bigpass(
    const float* __restrict__ inp, u16* __restrict__ xhat,
    const u16* __restrict__ qbuf16,
    const float* __restrict__ lng, const float* __restrict__ lnb,
    float* __restrict__ PU, float* __restrict__ PS){
  int b = blockIdx.y, chunk = blockIdx.x, t = threadIdx.x;
  int w = t>>6, lane = t&63;
  int fr = lane&15, fq = lane>>4;
  __shared__ __align__(16) u16 xt[256*64];      // 32 KB, XOR-swizzled rows (128B/row)
  __shared__ __align__(16) u16 qA[16*64];       // 2 KB, swizzled
  __shared__ float UL[4][512];
  __shared__ float SL[4][8];

  // stage q-tilde A-tile (bf16 [16][64])
  if (t < 128){
    uint4 v = ((const uint4*)(qbuf16 + b*1024))[t];
    int row = t>>3;
    *(uint4*)((char*)qA + ((t*16) ^ ((row&7)<<4))) = v;
  }
  long base = (long)b*N_ + (long)chunk*CHUNK;
  if (FUSED){
    // LN from f32 inputs: 4 threads per row, 4 passes of 64 rows
    #pragma unroll
    for (int p=0;p<4;++p){
      int r = p*64 + (t>>2);
      const float4* xr = (const float4*)(inp + (base + r)*64 + (t&3)*16);
      float xv[16]; float s=0.f, sq=0.f;
      #pragma unroll
      for (int c=0;c<4;++c){
        float4 f = xr[c];
        xv[c*4+0]=f.x; xv[c*4+1]=f.y; xv[c*4+2]=f.z; xv[c*4+3]=f.w;
        s  += f.x+f.y+f.z+f.w;
        sq += f.x*f.x+f.y*f.y+f.z*f.z+f.w*f.w;
      }
      s  += __shfl_xor(s, 1, 64);  s  += __shfl_xor(s, 2, 64);
      sq += __shfl_xor(sq, 1, 64); sq += __shfl_xor(sq, 2, 64);
      float mean = s*(1.f/64.f);
      float inv  = rsqrtf(sq*(1.f/64.f) - mean*mean + EPS_LN);
      u32 pk[8];
      #pragma unroll
      for (int e=0;e<8;++e){
        int d0 = (t&3)*16 + e*2;
        float a0 = (xv[e*2]  -mean)*inv*lng[d0]   + lnb[d0];
        float a1 = (xv[e*2+1]-mean)*inv*lng[d0+1] + lnb[d0+1];
        pk[e] = (u32)f2bf(a0) | ((u32)f2bf(a1)<<16);
      }
      int byte0 = r*128 + (t&3)*32;
      uint4 v0; v0.x=pk[0]; v0.y=pk[1]; v0.z=pk[2]; v0.w=pk[3];
      uint4 v1; v1.x=pk[4]; v1.y=pk[5]; v1.z=pk[6]; v1.w=pk[7];
      *(uint4*)((char*)xt + ( byte0      ^ ((r&7)<<4))) = v0;
      *(uint4*)((char*)xt + ((byte0+16)  ^ ((r&7)<<4))) = v1;
    }
    __syncthreads();
    // write xhat for later iterations (coalesced)
    uint4* gdst = (uint4*)(xhat + base*64);
    #pragma unroll
    for (int j=0;j<8;++j){
      int ch = t + j*256;
      int row = ch>>3;
      gdst[ch] = *(const uint4*)((char*)xt + ((ch*16) ^ ((row&7)<<4)));
    }
  } else {
    const uint4* gsrc = (const uint4*)(xhat + base*64);
    #pragma unroll
    for (int j=0;j<8;++j){
      int ch = t + j*256;
      uint4 v = gsrc[ch];
      int row = ch>>3;
      *(uint4*)((char*)xt + ((ch*16) ^ ((row&7)<<4))) = v;
    }
    __syncthreads();
  }

  // phase 1: dots via MFMA. A = q-tilde [16 slots x 64], B = xt rows (positions).
  f32x4 acc[4];
  #pragma unroll
  for (int nt=0;nt<4;++nt) acc[nt] = (f32x4){0.f,0.f,0.f,0.f};
  short8 afr[2];
  #pragma unroll
  for (int kk=0;kk<2;++kk)
    afr[kk] = *(const short8*)((char*)qA + ((fr*128 + kk*64 + fq*16) ^ ((fr&7)<<4)));
  #pragma unroll
  for (int nt=0;nt<4;++nt){
    #pragma unroll
    for (int kk=0;kk<2;++kk){
      int pr = w*64 + nt*16 + fr;
      short8 bf = *(const short8*)((char*)xt + ((pr*128 + kk*64 + fq*16) ^ ((pr&7)<<4)));
      acc[nt] = __builtin_amdgcn_mfma_f32_16x16x32_bf16(afr[kk], bf, acc[nt], 0, 0, 0);
    }
  }
  // softmax over slots (C layout: row=slot=fq*4+reg, col=pos=nt*16+fr)
  float tslot[4] = {0.f,0.f,0.f,0.f};
  #pragma unroll
  for (int nt=0;nt<4;++nt){
    float d0 = acc[nt][0]*SCALE_, d1 = acc[nt][1]*SCALE_;
    float d2 = acc[nt][2]*SCALE_, d3 = acc[nt][3]*SCALE_;
    float m = fmaxf(fmaxf(d0,d1), fmaxf(d2,d3));
    m = fmaxf(m, __shfl_xor(m, 16, 64));
    float e0 = __expf(d0-m), e1 = __expf(d1-m), e2 = __expf(d2-m), e3 = __expf(d3-m);
    float sl = e0+e1+e2+e3;
    float inv = 1.f/(sl + __shfl_xor(sl, 16, 64));
    float a0 = e0*inv + EPS_A, a1 = e1*inv + EPS_A;
    float a2 = e2*inv + EPS_A, a3 = e3*inv + EPS_A;
    acc[nt][0]=a0; acc[nt][1]=a1; acc[nt][2]=a2; acc[nt][3]=a3;
    tslot[0]+=a0; tslot[1]+=a1; tslot[2]+=a2; tslot[3]+=a3;
  }
  #pragma unroll
  for (int mk=1; mk<16; mk<<=1){
    tslot[0] += __shfl_xor(tslot[0], mk, 64);
    tslot[1] += __shfl_xor(tslot[1], mk, 64);
    tslot[2] += __shfl_xor(tslot[2], mk, 64);
    tslot[3] += __shfl_xor(tslot[3], mk, 64);
  }
  if (fr==0 && fq<2){
    SL[w][fq*4+0]=tslot[0]; SL[w][fq*4+1]=tslot[1];
    SL[w][fq*4+2]=tslot[2]; SL[w][fq*4+3]=tslot[3];
  }

  // phase 2: lane=d; attn broadcast via v_readlane from wave-private acc regs
  float U[8];
  #pragma unroll
  for (int i=0;i<8;++i) U[i]=0.f;
  #pragma unroll
  for (int nt=0;nt<4;++nt){
    #pragma unroll
    for (int idx=0; idx<16; ++idx){
      int rt = w*64 + nt*16 + idx;
      u32 hv = *(const u16*)((char*)xt + ((rt*128 + lane*2) ^ ((rt&7)<<4)));
      float xv = bf_lo(hv);
      #pragma unroll
      for (int i=0;i<8;++i){
        float av = __int_as_float(__builtin_amdgcn_readlane(
                     __float_as_int(acc[nt][i&3]), (i>>2)*16 + idx));
        U[i] += av*xv;
      }
    }
  }
  #pragma unroll
  for (int i=0;i<8;++i) UL[w][i*64+lane] = U[i];
  __syncthreads();
  float s0 = UL[0][t]+UL[1][t]+UL[2][t]+UL[3][t];
  float s1 = UL[0][t+256]+UL[1][t+256]+UL[2][t+256]+UL[3][t+256];
  long pb = ((long)b*NCHUNK + chunk)*512;
  PU[pb + t]       = s0;
  PU[pb + t + 256] = s1;
  if (t < 8)
    PS[((long)b*NCHUNK + chunk)*8 + t] = SL[0][t]+SL[1][t]+SL[2][t]+SL[3][t];
}

// ---- reduce partials; updates = (U/S)@Wv; GRU + LN + MLP; next q-tilde ----
__global__ __launch_bounds__(512) void slot_update(
    const float* __restrict__ PU, const float* __restrict__ PS,
    float* __restrict__ slots,
    const float* __restrict__ WihT, const float* __restrict__ WhhT,
    const float* __restrict__ bih, const float* __restrict__ bhh,
    const float* __restrict__ W1, const float* __restrict__ b1,
    const float* __restrict__ W2, const float* __restrict__ b2,
    const float* __restrict__ lnffg, const float* __restrict__ lnffb,
    const float* __restrict__ lnsg, const float* __restrict__ lnsb,
    const float* __restrict__ Wq, const float* __restrict__ Wv,
    const float* __restrict__ WkT2,
    u16* __restrict__ qbuf16, float* __restrict__ dout, int last){
  int b = blockIdx.x, t = threadIdx.x;
  int i = t>>6, d = t&63;
  __shared__ float updL[K_][68];
  __shared__ float spL[K_][68];
  __shared__ float sfL[K_][68];
  __shared__ float hL[K_][132];
  float u=0.f;
  #pragma unroll 4
  for (int c=0;c<NCHUNK;++c) u += PU[((long)b*NCHUNK + c)*512 + t];
  float S=0.f;
  #pragma unroll 4
  for (int c=0;c<NCHUNK;++c) S += PS[((long)b*NCHUNK + c)*8 + i];
  float ut = u / S;
  float sp = slots[b*512 + t];
  sfL[i][d] = ut;
  spL[i][d] = sp;
  __syncthreads();
  float upd = 0.f;
  #pragma unroll 4
  for (int dd=0; dd<64; ++dd) upd += sfL[i][dd]*Wv[dd*64 + d];
  updL[i][d] = upd;
  __syncthreads();
  float gx0 = bih[d], gx1 = bih[64+d], gx2 = bih[128+d];
  float gh0 = bhh[d], gh1 = bhh[64+d], gh2 = bhh[128+d];
  #pragma unroll 4
  for (int dd=0; dd<64; ++dd){
    float uv = updL[i][dd];
    float sv = spL[i][dd];
    const float* wi = WihT + dd*192 + d;
    const float* wh = WhhT + dd*192 + d;
    gx0 += uv*wi[0]; gx1 += uv*wi[64]; gx2 += uv*wi[128];
    gh0 += sv*wh[0]; gh1 += sv*wh[64]; gh2 += sv*wh[128];
  }
  float rg = 1.f/(1.f+__expf(-(gx0+gh0)));
  float zg = 1.f/(1.f+__expf(-(gx1+gh1)));
  float ng = tanhf(gx2 + rg*gh2);
  float sn = (1.f-zg)*ng + zg*sp;
  float m1 = wsum64(sn)*(1.f/64.f);
  float df = sn-m1;
  float vv = wsum64(df*df)*(1.f/64.f);
  float sf = df*rsqrtf(vv+EPS_LN)*lnffg[d] + lnffb[d];
  sfL[i][d] = sf;
  __syncthreads();
  float h0 = b1[d], h1 = b1[64+d];
  #pragma unroll 4
  for (int dd=0;dd<64;++dd){
    float sv = sfL[i][dd];
    h0 += sv*W1[dd*128 + d];
    h1 += sv*W1[dd*128 + 64 + d];
  }
  h0 = fmaxf(h0, 0.f); h1 = fmaxf(h1, 0.f);
  hL[i][d] = h0; hL[i][d+64] = h1;
  __syncthreads();
  float o = b2[d];
  #pragma unroll 4
  for (int hh=0; hh<128; ++hh) o += hL[i][hh]*W2[hh*64 + d];
  float out = sf + o;
  slots[b*512 + t] = out;
  if (last){
    dout[b*512 + t] = out;
  } else {
    float m2 = wsum64(out)*(1.f/64.f);
    float d2 = out-m2;
    float v2 = wsum64(d2*d2)*(1.f/64.f);
    float sq = d2*rsqrtf(v2+EPS_LN)*lnsg[d] + lnsb[d];
    updL[i][d] = sq;
    __syncthreads();
    float qv=0.f;
    #pragma unroll 8
    for (int dd=0;dd<64;++dd) qv += updL[i][dd]*Wq[dd*64 + d];
    __syncthreads();
    updL[i][d] = qv;
    __syncthreads();
    float qt=0.f;
    #pragma unroll 8
    for (int dd=0;dd<64;++dd) qt += updL[i][dd]*WkT2[dd*64 + d];
    qbuf16[b*1024 + t] = f2bf(qt);
    qbuf16[b*1024 + 512 + t] = 0;
  }
}

extern "C" void kernel_launch(void* const* d_in, const int* in_sizes, int n_in,
                              void* d_out, int out_size, void* d_ws, size_t ws_size,
                              hipStream_t stream){
  const float* inp   = (const float*)d_in[0];
  const float* noise = (const float*)d_in[1];
  const float* mu    = (const float*)d_in[2];
  const float* sigma = (const float*)d_in[3];
  const float* Wq    = (const float*)d_in[4];
  const float* Wk    = (const float*)d_in[5];
  const float* Wv    = (const float*)d_in[6];
  const float* Wih   = (const float*)d_in[7];
  const float* Whh   = (const float*)d_in[8];
  const float* bih   = (const float*)d_in[9];
  const float* bhh   = (const float*)d_in[10];
  const float* W1    = (const float*)d_in[11];
  const float* b1    = (const float*)d_in[12];
  const float* W2    = (const float*)d_in[13];
  const float* b2    = (const float*)d_in[14];
  const float* lnig  = (const float*)d_in[15];
  const float* lnib  = (const float*)d_in[16];
  const float* lnsg  = (const float*)d_in[17];
  const float* lnsb  = (const float*)d_in[18];
  const float* lnffg = (const float*)d_in[19];
  const float* lnffb = (const float*)d_in[20];
  float* out = (float*)d_out;

  char* ws = (char*)d_ws;
  u16*   xhat   = (u16*)(ws);                      // 67108864 B
  u16*   qbuf16 = (u16*)(ws + 67108864);           // 262144 B
  float* slots  = (float*)(ws + 67371008);         // 262144 B
  float* PU     = (float*)(ws + 67633152);         // 4194304 B
  float* PS     = (float*)(ws + 71827456);         // 65536 B
  float* WihT   = (float*)(ws + 71892992);         // 49152 B
  float* WhhT   = (float*)(ws + 71942144);         // 49152 B
  float* WkT2   = (float*)(ws + 71991296);         // 16384 B -> ~72 MB total

  prep_t<<<48,256,0,stream>>>(Wih, Whh, Wk, WihT, WhhT, WkT2);
  slots_init<<<B_,512,0,stream>>>(noise, mu, sigma, Wq, WkT2, lnsg, lnsb, slots, qbuf16);
  for (int it=0; it<ITERS_; ++it){
    if (it==0)
      bigpass<1><<<dim3(NCHUNK,B_),256,0,stream>>>(inp, xhat, qbuf16, lnig, lnib, PU, PS);
    else
      bigpass<0><<<dim3(NCHUNK,B_),256,0,stream>>>(inp, xhat, qbuf16, lnig, lnib, PU, PS);
    slot_update<<<B_,512,0,stream>>>(PU, PS, slots, WihT, WhhT, bih, bhh,
                                     W1, b1, W2, b2, lnffg, lnffb, lnsg, lnsb,
                                     Wq, Wv, WkT2, qbuf16, out, (it==ITERS_-1)?1:0);
  }
}

// Round 6
// 179.781 us; speedup vs baseline: 1.7914x; 1.0971x over previous
//
#include <hip/hip_runtime.h>
#include <hip/hip_bf16.h>

typedef unsigned int u32;
typedef unsigned short u16;
typedef __attribute__((ext_vector_type(8))) short short8;
typedef __attribute__((ext_vector_type(4))) float f32x4;

#define B_      128
#define N_      4096
#define D_      64
#define K_      8
#define H_      128
#define ITERS_  3
#define NCHUNK  32
#define CHUNK   128
#define SCALE_  0.125f
#define EPS_A   1e-8f
#define EPS_LN  1e-5f

__device__ __forceinline__ float bf_lo(u32 u){ union{u32 v; float f;} x; x.v = u<<16; return x.f; }
__device__ __forceinline__ u16 f2bf(float f){
  union{float f; u32 v;} x; x.f = f;
  u32 v = x.v;
  return (u16)((v + 0x7fffu + ((v>>16)&1u))>>16);   // RNE
}
__device__ __forceinline__ float wsum64(float v){
  #pragma unroll
  for (int off=32; off; off>>=1) v += __shfl_xor(v, off, 64);
  return v;
}
// xtT bank-spread swizzle selector
__device__ __forceinline__ int swT(int d){ return ((d ^ (d>>3)) & 7) << 4; }

// ---- one-time prep: transpose GRU weights; WkT2[dd][d] = Wk[d][dd] ----
__global__ void prep_t(const float* __restrict__ Wih, const float* __restrict__ Whh,
                       const float* __restrict__ Wk,
                       float* __restrict__ WihT, float* __restrict__ WhhT,
                       float* __restrict__ WkT2){
  int idx = blockIdx.x*256 + threadIdx.x;   // 48*256 = 12288
  if (idx < 192*64){
    int g = idx>>6, d = idx&63;
    WihT[d*192+g] = Wih[idx];
    WhhT[d*192+g] = Whh[idx];
  }
  if (idx < 4096){
    int dd = idx>>6, d = idx&63;
    WkT2[idx] = Wk[d*64+dd];
  }
}

// ---- slots0 = mu + sigma*noise ; q = LN(slots0)@Wq ; qt = q@Wk^T (bf16, padded 16 rows) ----
__global__ __launch_bounds__(512) void slots_init(
    const float* __restrict__ noise, const float* __restrict__ mu, const float* __restrict__ sigma,
    const float* __restrict__ Wq, const float* __restrict__ WkT2,
    const float* __restrict__ lnsg, const float* __restrict__ lnsb,
    float* __restrict__ slots, u16* __restrict__ qbuf16){
  int b = blockIdx.x, t = threadIdx.x;
  int i = t>>6, d = t&63;
  __shared__ float svL[K_][68];
  float s0 = mu[d] + sigma[d]*noise[b*512 + t];
  slots[b*512 + t] = s0;
  float m  = wsum64(s0) * (1.f/64.f);
  float df = s0 - m;
  float vv = wsum64(df*df) * (1.f/64.f);
  float sv = df * rsqrtf(vv + EPS_LN) * lnsg[d] + lnsb[d];
  svL[i][d] = sv;
  __syncthreads();
  float q = 0.f;
  #pragma unroll 8
  for (int dd=0; dd<64; ++dd) q += svL[i][dd] * Wq[dd*64 + d];
  __syncthreads();
  svL[i][d] = q;
  __syncthreads();
  float qt = 0.f;
  #pragma unroll 8
  for (int dd=0; dd<64; ++dd) qt += svL[i][dd] * WkT2[dd*64 + d];
  qbuf16[b*1024 + t] = f2bf(qt);
  qbuf16[b*1024 + 512 + t] = 0;          // pad rows 8..15
}

// ---- fused: (iter0) LN + dots(MFMA) + softmax-over-K + PV(MFMA) partials ----
template<int FUSED>
__global__ __launch_bounds__(256,4) void bigpass(
    const float* __restrict__ inp, u16* __restrict__ xhat,
    const u16* __restrict__ qbuf16,
    const float* __restrict__ lng, const float* __restrict__ lnb,
    float* __restrict__ PU, float* __restrict__ PS){
  int b = blockIdx.y, chunk = blockIdx.x, t = threadIdx.x;
  int w = t>>6, lane = t&63;
  int fr = lane&15, fq = lane>>4;

  // LDS map (manual aliasing):
  //  [0,16384)      xt   [128 pos][64 d] u16, byte ^ ((pos&7)<<4)   -- dead after phase 1
  //     alias: [0,8704) UL [4][8][68] f32 ; [8704,12800) abuf [4][1024B]
  //  [16384,32768)  xtT  [64 d][128 pos] u16, (pos*2) ^ swT(d)
  //  [32768,34816)  qA   [16][64] u16, byte ^ ((row&7)<<4)
  __shared__ __align__(16) char smem[34816];
  char*  xt   = smem;
  float* UL   = (float*)smem;
  char*  abuf = smem + 8704;
  char*  xtT  = smem + 16384;
  char*  qA   = smem + 32768;
  __shared__ float SL[4][8];

  if (t < 128){
    uint4 v = ((const uint4*)(qbuf16 + b*1024))[t];
    int row = t>>3;
    *(uint4*)(qA + ((t*16) ^ ((row&7)<<4))) = v;
  }
  long base = (long)b*N_ + (long)chunk*CHUNK;
  if (FUSED){
    // LN from f32 inputs: 4 threads per row, 2 passes of 64 rows
    #pragma unroll
    for (int p=0;p<2;++p){
      int r = p*64 + (t>>2);
      int q = t&3;
      const float4* xr = (const float4*)(inp + (base + r)*64 + q*16);
      float xv[16]; float s=0.f, sq=0.f;
      #pragma unroll
      for (int c=0;c<4;++c){
        float4 f = xr[c];
        xv[c*4+0]=f.x; xv[c*4+1]=f.y; xv[c*4+2]=f.z; xv[c*4+3]=f.w;
        s  += f.x+f.y+f.z+f.w;
        sq += f.x*f.x+f.y*f.y+f.z*f.z+f.w*f.w;
      }
      s  += __shfl_xor(s, 1, 64);  s  += __shfl_xor(s, 2, 64);
      sq += __shfl_xor(sq, 1, 64); sq += __shfl_xor(sq, 2, 64);
      float mean = s*(1.f/64.f);
      float inv  = rsqrtf(sq*(1.f/64.f) - mean*mean + EPS_LN);
      u32 pk[8];
      #pragma unroll
      for (int e=0;e<8;++e){
        int d0 = q*16 + e*2;
        float a0 = (xv[e*2]  -mean)*inv*lng[d0]   + lnb[d0];
        float a1 = (xv[e*2+1]-mean)*inv*lng[d0+1] + lnb[d0+1];
        pk[e] = (u32)f2bf(a0) | ((u32)f2bf(a1)<<16);
      }
      uint4 v0; v0.x=pk[0]; v0.y=pk[1]; v0.z=pk[2]; v0.w=pk[3];
      uint4 v1; v1.x=pk[4]; v1.y=pk[5]; v1.z=pk[6]; v1.w=pk[7];
      // global xhat (row-major, coalesced)
      uint4* gdst = (uint4*)(xhat + (base + r)*64);
      gdst[q*2]   = v0;
      gdst[q*2+1] = v1;
      // xt (row-major swizzled)
      int byte0 = r*128 + q*32;
      *(uint4*)(xt + ( byte0      ^ ((r&7)<<4))) = v0;
      *(uint4*)(xt + ((byte0+16)  ^ ((r&7)<<4))) = v1;
      // xtT (transposed, scalar writes)
      #pragma unroll
      for (int e=0;e<16;++e){
        int d = q*16 + e;
        u16 hv = (e&1) ? (u16)(pk[e>>1]>>16) : (u16)(pk[e>>1]&0xffffu);
        *(u16*)(xtT + d*256 + ((r*2) ^ swT(d))) = hv;
      }
    }
  } else {
    const uint4* gsrc = (const uint4*)(xhat + base*64);
    #pragma unroll
    for (int j=0;j<4;++j){
      int ch = t + j*256;
      uint4 v = gsrc[ch];
      int row = ch>>3, dblk = ch&7;
      *(uint4*)(xt + ((ch*16) ^ ((row&7)<<4))) = v;
      u32 wsv[4] = {v.x, v.y, v.z, v.w};
      #pragma unroll
      for (int e2=0;e2<4;++e2){
        #pragma unroll
        for (int h=0;h<2;++h){
          int d = dblk*8 + e2*2 + h;
          u16 hv = h ? (u16)(wsv[e2]>>16) : (u16)(wsv[e2]&0xffffu);
          *(u16*)(xtT + d*256 + ((row*2) ^ swT(d))) = hv;
        }
      }
    }
  }
  __syncthreads();   // bar1: tiles ready

  // ---- phase 1: dots = mfma(q-tilde, xhat-rows) -> D[slot][pos] ----
  f32x4 c1[2];
  c1[0] = (f32x4){0.f,0.f,0.f,0.f};
  c1[1] = (f32x4){0.f,0.f,0.f,0.f};
  short8 qf[2];
  #pragma unroll
  for (int kk=0;kk<2;++kk)
    qf[kk] = *(const short8*)(qA + ((fr*128 + kk*64 + fq*16) ^ ((fr&7)<<4)));
  #pragma unroll
  for (int nt=0;nt<2;++nt){
    #pragma unroll
    for (int kk=0;kk<2;++kk){
      int pos = w*32 + nt*16 + fr;
      short8 xf = *(const short8*)(xt + ((pos*128 + kk*64 + fq*16) ^ ((pos&7)<<4)));
      c1[nt] = __builtin_amdgcn_mfma_f32_16x16x32_bf16(qf[kk], xf, c1[nt], 0, 0, 0);
    }
  }
  // softmax over slots (rows): slot = fq*4+r (valid fq<2), col pos = nt*16+fr
  float tslot[4] = {0.f,0.f,0.f,0.f};
  #pragma unroll
  for (int nt=0;nt<2;++nt){
    float d0 = c1[nt][0]*SCALE_, d1 = c1[nt][1]*SCALE_;
    float d2 = c1[nt][2]*SCALE_, d3 = c1[nt][3]*SCALE_;
    float m = fmaxf(fmaxf(d0,d1), fmaxf(d2,d3));
    m = fmaxf(m, __shfl_xor(m, 16, 64));
    float e0 = __expf(d0-m), e1 = __expf(d1-m), e2 = __expf(d2-m), e3 = __expf(d3-m);
    float sl = e0+e1+e2+e3;
    float inv = 1.f/(sl + __shfl_xor(sl, 16, 64));
    float a0 = e0*inv + EPS_A, a1 = e1*inv + EPS_A;
    float a2 = e2*inv + EPS_A, a3 = e3*inv + EPS_A;
    c1[nt][0]=a0; c1[nt][1]=a1; c1[nt][2]=a2; c1[nt][3]=a3;
    tslot[0]+=a0; tslot[1]+=a1; tslot[2]+=a2; tslot[3]+=a3;
  }
  #pragma unroll
  for (int mk=1; mk<16; mk<<=1){
    tslot[0] += __shfl_xor(tslot[0], mk, 64);
    tslot[1] += __shfl_xor(tslot[1], mk, 64);
    tslot[2] += __shfl_xor(tslot[2], mk, 64);
    tslot[3] += __shfl_xor(tslot[3], mk, 64);
  }
  if (fr==0 && fq<2){
    SL[w][fq*4+0]=tslot[0]; SL[w][fq*4+1]=tslot[1];
    SL[w][fq*4+2]=tslot[2]; SL[w][fq*4+3]=tslot[3];
  }
  __syncthreads();   // bar2: xt dead -> abuf/UL aliases safe

  // ---- abuf: attn into P-frag order: abuf[w][lane2][j] = attn[slot=lane2&15][pos=w*32+(lane2>>4)*8+j]
  #pragma unroll
  for (int nt=0;nt<2;++nt){
    #pragma unroll
    for (int r=0;r<4;++r){
      int slot16 = fq*4 + r;                       // 0..15 (8..15 junk, lands in unused rows)
      int lane2  = (nt*2 + (fr>>3))*16 + slot16;
      int j      = fr & 7;
      int byte   = w*1024 + ((lane2*16 + j*2) ^ (((lane2>>3)&7)<<4));
      *(u16*)(abuf + byte) = f2bf(c1[nt][r]);
    }
  }
  // ---- phase 2: U[slot][d] = mfma(attn-frag, xtT-frag) per d-block ----
  short8 pf = *(const short8*)(abuf + w*1024 + ((lane*16) ^ (((lane>>3)&7)<<4)));
  f32x4 c2[4];
  #pragma unroll
  for (int dblk=0;dblk<4;++dblk){
    int d = dblk*16 + fr;
    short8 xtf = *(const short8*)(xtT + d*256 + ((w*64 + fq*16) ^ swT(d)));
    f32x4 z = (f32x4){0.f,0.f,0.f,0.f};
    c2[dblk] = __builtin_amdgcn_mfma_f32_16x16x32_bf16(pf, xtf, z, 0, 0, 0);
  }
  // UL[w][slot][d] (slot = fq*4+r, valid fq<2; d = dblk*16+fr)
  if (fq < 2){
    #pragma unroll
    for (int dblk=0;dblk<4;++dblk){
      #pragma unroll
      for (int r=0;r<4;++r)
        UL[(w*8 + fq*4 + r)*68 + dblk*16 + fr] = c2[dblk][r];
    }
  }
  __syncthreads();   // bar3
  // ---- cross-wave reduce -> PU, PS ----
  {
    int s = t>>6, d = t&63;
    float v0 = UL[(0*8+s)*68+d] + UL[(1*8+s)*68+d] + UL[(2*8+s)*68+d] + UL[(3*8+s)*68+d];
    int s2 = s+4;
    float v1 = UL[(0*8+s2)*68+d] + UL[(1*8+s2)*68+d] + UL[(2*8+s2)*68+d] + UL[(3*8+s2)*68+d];
    long pb = ((long)b*NCHUNK + chunk)*512;
    PU[pb + s*64 + d]  = v0;
    PU[pb + s2*64 + d] = v1;
  }
  if (t < 8)
    PS[((long)b*NCHUNK + chunk)*8 + t] = SL[0][t]+SL[1][t]+SL[2][t]+SL[3][t];
}

// ---- reduce partials; updates = (U/S)@Wv; GRU + LN + MLP; next q-tilde ----
__global__ __launch_bounds__(512) void slot_update(
    const float* __restrict__ PU, const float* __restrict__ PS,
    float* __restrict__ slots,
    const float* __restrict__ WihT, const float* __restrict__ WhhT,
    const float* __restrict__ bih, const float* __restrict__ bhh,
    const float* __restrict__ W1, const float* __restrict__ b1,
    const float* __restrict__ W2, const float* __restrict__ b2,
    const float* __restrict__ lnffg, const float* __restrict__ lnffb,
    const float* __restrict__ lnsg, const float* __restrict__ lnsb,
    const float* __restrict__ Wq, const float* __restrict__ Wv,
    const float* __restrict__ WkT2,
    u16* __restrict__ qbuf16, float* __restrict__ dout, int last){
  int b = blockIdx.x, t = threadIdx.x;
  int i = t>>6, d = t&63;
  __shared__ float updL[K_][68];
  __shared__ float spL[K_][68];
  __shared__ float sfL[K_][68];
  __shared__ float hL[K_][132];
  float u=0.f;
  #pragma unroll 4
  for (int c=0;c<NCHUNK;++c) u += PU[((long)b*NCHUNK + c)*512 + t];
  float S=0.f;
  #pragma unroll 4
  for (int c=0;c<NCHUNK;++c) S += PS[((long)b*NCHUNK + c)*8 + i];
  float ut = u / S;
  float sp = slots[b*512 + t];
  sfL[i][d] = ut;
  spL[i][d] = sp;
  __syncthreads();
  float upd = 0.f;
  #pragma unroll 4
  for (int dd=0; dd<64; ++dd) upd += sfL[i][dd]*Wv[dd*64 + d];
  updL[i][d] = upd;
  __syncthreads();
  float gx0 = bih[d], gx1 = bih[64+d], gx2 = bih[128+d];
  float gh0 = bhh[d], gh1 = bhh[64+d], gh2 = bhh[128+d];
  #pragma unroll 4
  for (int dd=0; dd<64; ++dd){
    float uv = updL[i][dd];
    float sv = spL[i][dd];
    const float* wi = WihT + dd*192 + d;
    const float* wh = WhhT + dd*192 + d;
    gx0 += uv*wi[0]; gx1 += uv*wi[64]; gx2 += uv*wi[128];
    gh0 += sv*wh[0]; gh1 += sv*wh[64]; gh2 += sv*wh[128];
  }
  float rg = 1.f/(1.f+__expf(-(gx0+gh0)));
  float zg = 1.f/(1.f+__expf(-(gx1+gh1)));
  float ng = tanhf(gx2 + rg*gh2);
  float sn = (1.f-zg)*ng + zg*sp;
  float m1 = wsum64(sn)*(1.f/64.f);
  float df = sn-m1;
  float vv = wsum64(df*df)*(1.f/64.f);
  float sf = df*rsqrtf(vv+EPS_LN)*lnffg[d] + lnffb[d];
  sfL[i][d] = sf;
  __syncthreads();
  float h0 = b1[d], h1 = b1[64+d];
  #pragma unroll 4
  for (int dd=0;dd<64;++dd){
    float sv = sfL[i][dd];
    h0 += sv*W1[dd*128 + d];
    h1 += sv*W1[dd*128 + 64 + d];
  }
  h0 = fmaxf(h0, 0.f); h1 = fmaxf(h1, 0.f);
  hL[i][d] = h0; hL[i][d+64] = h1;
  __syncthreads();
  float o = b2[d];
  #pragma unroll 4
  for (int hh=0; hh<128; ++hh) o += hL[i][hh]*W2[hh*64 + d];
  float out = sf + o;
  slots[b*512 + t] = out;
  if (last){
    dout[b*512 + t] = out;
  } else {
    float m2 = wsum64(out)*(1.f/64.f);
    float d2 = out-m2;
    float v2 = wsum64(d2*d2)*(1.f/64.f);
    float sq = d2*rsqrtf(v2+EPS_LN)*lnsg[d] + lnsb[d];
    updL[i][d] = sq;
    __syncthreads();
    float qv=0.f;
    #pragma unroll 8
    for (int dd=0;dd<64;++dd) qv += updL[i][dd]*Wq[dd*64 + d];
    __syncthreads();
    updL[i][d] = qv;
    __syncthreads();
    float qt=0.f;
    #pragma unroll 8
    for (int dd=0;dd<64;++dd) qt += updL[i][dd]*WkT2[dd*64 + d];
    qbuf16[b*1024 + t] = f2bf(qt);
    qbuf16[b*1024 + 512 + t] = 0;
  }
}

extern "C" void kernel_launch(void* const* d_in, const int* in_sizes, int n_in,
                              void* d_out, int out_size, void* d_ws, size_t ws_size,
                              hipStream_t stream){
  const float* inp   = (const float*)d_in[0];
  const float* noise = (const float*)d_in[1];
  const float* mu    = (const float*)d_in[2];
  const float* sigma = (const float*)d_in[3];
  const float* Wq    = (const float*)d_in[4];
  const float* Wk    = (const float*)d_in[5];
  const float* Wv    = (const float*)d_in[6];
  const float* Wih   = (const float*)d_in[7];
  const float* Whh   = (const float*)d_in[8];
  const float* bih   = (const float*)d_in[9];
  const float* bhh   = (const float*)d_in[10];
  const float* W1    = (const float*)d_in[11];
  const float* b1    = (const float*)d_in[12];
  const float* W2    = (const float*)d_in[13];
  const float* b2    = (const float*)d_in[14];
  const float* lnig  = (const float*)d_in[15];
  const float* lnib  = (const float*)d_in[16];
  const float* lnsg  = (const float*)d_in[17];
  const float* lnsb  = (const float*)d_in[18];
  const float* lnffg = (const float*)d_in[19];
  const float* lnffb = (const float*)d_in[20];
  float* out = (float*)d_out;

  char* ws = (char*)d_ws;
  u16*   xhat   = (u16*)(ws);                      // 67108864 B
  u16*   qbuf16 = (u16*)(ws + 67108864);           // 262144 B
  float* slots  = (float*)(ws + 67371008);         // 262144 B
  float* PU     = (float*)(ws + 67633152);         // 128*32*512*4 = 8388608 B
  float* PS     = (float*)(ws + 76021760);         // 128*32*8*4   = 131072 B
  float* WihT   = (float*)(ws + 76152832);         // 49152 B
  float* WhhT   = (float*)(ws + 76201984);         // 49152 B
  float* WkT2   = (float*)(ws + 76251136);         // 16384 B -> ~76.3 MB total

  prep_t<<<48,256,0,stream>>>(Wih, Whh, Wk, WihT, WhhT, WkT2);
  slots_init<<<B_,512,0,stream>>>(noise, mu, sigma, Wq, WkT2, lnsg, lnsb, slots, qbuf16);
  for (int it=0; it<ITERS_; ++it){
    if (it==0)
      bigpass<1><<<dim3(NCHUNK,B_),256,0,stream>>>(inp, xhat, qbuf16, lnig, lnib, PU, PS);
    else
      bigpass<0><<<dim3(NCHUNK,B_),256,0,stream>>>(inp, xhat, qbuf16, lnig, lnib, PU, PS);
    slot_update<<<B_,512,0,stream>>>(PU, PS, slots, WihT, WhhT, bih, bhh,
                                     W1, b1, W2, b2, lnffg, lnffb, lnsg, lnsb,
                                     Wq, Wv, WkT2, qbuf16, out, (it==ITERS_-1)?1:0);
  }
}